// Round 1
// baseline (116.720 us; speedup 1.0000x reference)
//
#include <hip/hip_runtime.h>
#include <math.h>

#define S_LEN 4096
#define B_COLS 64
#define HDIM   512

// Kernel 1: s[t,b] = dot(hidden_states[t,b,:], W[:,0]) + b[0]
// One 64-lane wave per row; 2 coalesced float4 loads per lane (covers 512 floats).
__global__ __launch_bounds__(256) void fc_scores_kernel(
    const float* __restrict__ hs,
    const float* __restrict__ W,
    const float* __restrict__ bias,
    float* __restrict__ s_out,
    int rows) {
  const int lane = threadIdx.x & 63;
  const int wid  = (blockIdx.x * blockDim.x + threadIdx.x) >> 6;
  const int nw   = (gridDim.x * blockDim.x) >> 6;

  const float4* W4 = reinterpret_cast<const float4*>(W);
  const float4 wv0 = W4[lane];        // elements [4*lane, 4*lane+4)
  const float4 wv1 = W4[64 + lane];   // elements [256+4*lane, ...)
  const float  bb  = bias[0];

  for (int row = wid; row < rows; row += nw) {
    const float4* H4 = reinterpret_cast<const float4*>(hs + (size_t)row * HDIM);
    float4 h0 = H4[lane];
    float4 h1 = H4[64 + lane];
    float p = h0.x * wv0.x + h0.y * wv0.y + h0.z * wv0.z + h0.w * wv0.w
            + h1.x * wv1.x + h1.y * wv1.y + h1.z * wv1.z + h1.w * wv1.w;
    #pragma unroll
    for (int m = 32; m >= 1; m >>= 1) p += __shfl_xor(p, m, 64);
    if (lane == 0) s_out[row] = p + bb;
  }
}

// Kernel 2: per-column (b) reverse cumulative logsumexp, then
// selected[t,b] = exp(s[t,b] - suffix_lse[t,b]). In-place on the score buffer.
// One block per column; 256 threads; each thread owns 16 consecutive t.
__global__ __launch_bounds__(256) void suffix_softmax_kernel(float* __restrict__ sbuf) {
  const int b   = blockIdx.x;
  const int tid = threadIdx.x;
  constexpr int NT  = 256;
  constexpr int PER = S_LEN / NT;  // 16

  __shared__ float col[S_LEN];   // 16 KiB
  __shared__ float sm[NT];
  __shared__ float sz[NT];

  // Stage the column into LDS.
  for (int t = tid; t < S_LEN; t += NT)
    col[t] = sbuf[(size_t)t * B_COLS + b];
  __syncthreads();

  const int base = tid * PER;

  // Local (max, sumexp) aggregate over this thread's 16 elements.
  float m = -INFINITY, z = 0.f;
  #pragma unroll
  for (int j = 0; j < PER; ++j) {
    float v  = col[base + j];
    float nm = fmaxf(m, v);
    z = z * expf(m - nm) + expf(v - nm);
    m = nm;
  }
  sm[tid] = m; sz[tid] = z;
  __syncthreads();

  // Reverse inclusive Hillis-Steele scan over the 256 aggregates
  // with the logsumexp combine: (m,z) <- (m,z) ⊕ (m',z') for partner tid+off.
  for (int off = 1; off < NT; off <<= 1) {
    float om = -INFINITY, oz = 0.f;
    if (tid + off < NT) { om = sm[tid + off]; oz = sz[tid + off]; }
    __syncthreads();
    float nm = fmaxf(m, om);
    z = z * expf(m - nm) + oz * expf(om - nm);
    m = nm;
    sm[tid] = m; sz[tid] = z;
    __syncthreads();
  }

  // Exclusive suffix for this thread = inclusive scan of thread tid+1.
  float em = -INFINITY, ez = 0.f;
  if (tid + 1 < NT) { em = sm[tid + 1]; ez = sz[tid + 1]; }

  // Serial reverse pass within the chunk; emit selected = exp(s - m)/z.
  #pragma unroll
  for (int j = PER - 1; j >= 0; --j) {
    float v  = col[base + j];
    float nm = fmaxf(em, v);
    float e  = expf(v - nm);
    ez = ez * expf(em - nm) + e;
    em = nm;
    sbuf[(size_t)(base + j) * B_COLS + b] = e / ez;
  }
}

extern "C" void kernel_launch(void* const* d_in, const int* in_sizes, int n_in,
                              void* d_out, int out_size, void* d_ws, size_t ws_size,
                              hipStream_t stream) {
  const float* hs   = (const float*)d_in[0];
  const float* W    = (const float*)d_in[1];
  const float* bias = (const float*)d_in[2];
  float* out = (float*)d_out;   // [S, B, 1] == S*B floats; doubles as score scratch

  const int rows = S_LEN * B_COLS;  // 262144
  fc_scores_kernel<<<2048, 256, 0, stream>>>(hs, W, bias, out, rows);
  suffix_softmax_kernel<<<B_COLS, 256, 0, stream>>>(out);
}

// Round 2
// 93.457 us; speedup vs baseline: 1.2489x; 1.2489x over previous
//
#include <hip/hip_runtime.h>
#include <math.h>

#define S_LEN  4096
#define B_COLS 64
#define HDIM   512

typedef float v4f __attribute__((ext_vector_type(4)));

// Kernel 1: s[t,b] = dot(hidden_states[t,b,:], W[:,0]) + b[0]
// One 64-lane wave per 4 rows per iteration; 8 independent 16B nontemporal
// loads in flight. Scores written TRANSPOSED to ws[b*S + t] for kernel 2.
__global__ __launch_bounds__(256) void fc_scores_kernel(
    const float* __restrict__ hs,
    const float* __restrict__ W,
    const float* __restrict__ bias,
    float* __restrict__ ws) {
  const int lane = threadIdx.x & 63;
  const int wid  = (blockIdx.x * blockDim.x + threadIdx.x) >> 6;  // 0..8191
  constexpr int NW   = 2048 * 4;       // total waves
  constexpr int ROWS = S_LEN * B_COLS; // 262144

  const v4f* W4 = reinterpret_cast<const v4f*>(W);
  const v4f wv0 = W4[lane];
  const v4f wv1 = W4[64 + lane];
  const float bb = bias[0];

  for (int r0 = wid * 4; r0 < ROWS; r0 += NW * 4) {
    float p[4];
    #pragma unroll
    for (int u = 0; u < 4; ++u) {
      const v4f* H4 = reinterpret_cast<const v4f*>(hs + (size_t)(r0 + u) * HDIM);
      v4f a = __builtin_nontemporal_load(&H4[lane]);
      v4f c = __builtin_nontemporal_load(&H4[64 + lane]);
      p[u] = a.x * wv0.x + a.y * wv0.y + a.z * wv0.z + a.w * wv0.w
           + c.x * wv1.x + c.y * wv1.y + c.z * wv1.z + c.w * wv1.w;
    }
    #pragma unroll
    for (int m = 32; m >= 1; m >>= 1) {
      #pragma unroll
      for (int u = 0; u < 4; ++u) p[u] += __shfl_xor(p[u], m, 64);
    }
    if (lane == 0) {
      #pragma unroll
      for (int u = 0; u < 4; ++u) {
        int row = r0 + u;
        int t = row >> 6, b = row & 63;
        ws[(size_t)b * S_LEN + t] = p[u] + bb;
      }
    }
  }
}

// Kernel 2: per-column reverse cumulative logsumexp + exp(s - lse).
// One block per column b; 1024 threads; thread owns 4 consecutive t loaded as
// one coalesced float4 from the transposed score buffer. 3-stage suffix scan:
// wave shuffle scan (no barriers) -> 16 wave aggregates in LDS (2 barriers).
__global__ __launch_bounds__(1024) void suffix_softmax_kernel(
    const float* __restrict__ ws, float* __restrict__ out) {
  const int b    = blockIdx.x;
  const int tid  = threadIdx.x;      // 0..1023
  const int lane = tid & 63;
  const int wv   = tid >> 6;         // 0..15
  constexpr int PER = 4;

  v4f v = *reinterpret_cast<const v4f*>(ws + (size_t)b * S_LEN + tid * PER);

  // Local aggregate over the thread's 4 elements.
  float m = fmaxf(fmaxf(v.x, v.y), fmaxf(v.z, v.w));
  float z = expf(v.x - m) + expf(v.y - m) + expf(v.z - m) + expf(v.w - m);

  // Wave reverse inclusive scan: (m,z)[lane] = aggregate of lanes [lane..63].
  #pragma unroll
  for (int off = 1; off < 64; off <<= 1) {
    float om = __shfl_down(m, off, 64);
    float oz = __shfl_down(z, off, 64);
    bool valid = (lane + off) < 64;
    om = valid ? om : -INFINITY;
    oz = valid ? oz : 0.f;
    float nm = fmaxf(m, om);
    z = z * expf(m - nm) + oz * expf(om - nm);  // om=-inf -> second term 0
    m = nm;
  }

  __shared__ float wm[16], wz[16];
  if (lane == 0) { wm[wv] = m; wz[wv] = z; }

  // Thread-exclusive suffix within the wave = inclusive value of lane+1.
  float em = __shfl_down(m, 1, 64);
  float ez = __shfl_down(z, 1, 64);
  if (lane == 63) { em = -INFINITY; ez = 0.f; }

  __syncthreads();

  // Wave-exclusive aggregate: combine waves wv+1..15 (broadcast LDS reads).
  float gm = -INFINITY, gz = 0.f;
  for (int w = wv + 1; w < 16; ++w) {
    float nm = fmaxf(gm, wm[w]);
    gz = gz * expf(gm - nm) + wz[w] * expf(wm[w] - nm);
    gm = nm;
  }

  // Total exclusive suffix for this thread (guard -inf - -inf = NaN).
  float tm = fmaxf(em, gm);
  float tz = (em > -INFINITY ? ez * expf(em - tm) : 0.f)
           + (gm > -INFINITY ? gz * expf(gm - tm) : 0.f);

  // Serial reverse pass over the 4 elements; emit selected = exp(s-M)/Z.
  float vals[4] = {v.x, v.y, v.z, v.w};
  float r[4];
  #pragma unroll
  for (int j = 3; j >= 0; --j) {
    float val = vals[j];
    float nm  = fmaxf(tm, val);
    float e   = expf(val - nm);
    tz = tz * expf(tm - nm) + e;   // tm=-inf -> first term 0 (nm finite)
    tm = nm;
    r[j] = e / tz;
  }
  #pragma unroll
  for (int j = 0; j < 4; ++j)
    out[(size_t)(tid * PER + j) * B_COLS + b] = r[j];
}

extern "C" void kernel_launch(void* const* d_in, const int* in_sizes, int n_in,
                              void* d_out, int out_size, void* d_ws, size_t ws_size,
                              hipStream_t stream) {
  const float* hs   = (const float*)d_in[0];
  const float* W    = (const float*)d_in[1];
  const float* bias = (const float*)d_in[2];
  float* out = (float*)d_out;       // [S, B, 1] == S*B floats
  float* ws  = (float*)d_ws;        // transposed scores [B][S], 1 MiB

  fc_scores_kernel<<<2048, 256, 0, stream>>>(hs, W, bias, ws);
  suffix_softmax_kernel<<<B_COLS, 1024, 0, stream>>>(ws, out);
}